// Round 4
// baseline (2278.206 us; speedup 1.0000x reference)
//
#include <hip/hip_runtime.h>

#define EPSV 1e-4f

// Level geometry (derived from reference shapes)
constexpr int D1=41, H1=264, W1=264; constexpr int S1=D1*H1*W1;   // 2,857,536
constexpr int D2=20, H2=131, W2=131; constexpr int S2=D2*H2*W2;   //   343,220
constexpr int D3=9,  H3=65,  W3=65;  constexpr int S3=D3*H3*W3;   //    38,025
constexpr int D4=4,  H4=32,  W4=32;  constexpr int S4=D4*H4*W4;   //     4,096
constexpr int DO_=2, HO_=32, WO_=32; constexpr int SO_=DO_*HO_*WO_; //   2,048
constexpr int NVOX_MAX=80000;

// ---- scatter voxel indices into dense grid; last-write-wins == max index (matches np) ----
__global__ void scatter_k(const int* __restrict__ coords, int n, int* __restrict__ grid1){
  int i = blockIdx.x*blockDim.x + threadIdx.x;
  if (i >= n) return;
  int z = coords[i*4+1], y = coords[i*4+2], x = coords[i*4+3];
  atomicMax(&grid1[(z*H1 + y)*W1 + x], i);
}

// ---- compact active sites of level 1 (block-aggregated atomics) ----
__global__ void compact1_k(int* __restrict__ grid1, int* __restrict__ act,
                           int* __restrict__ vox, int* __restrict__ cnt){
  __shared__ int lcnt, lbase;
  if (threadIdx.x == 0) lcnt = 0;
  __syncthreads();
  int p = blockIdx.x*blockDim.x + threadIdx.x;
  int v = (p < S1) ? grid1[p] : -1;
  int loc = -1;
  if (v >= 0) loc = atomicAdd(&lcnt, 1);
  __syncthreads();
  if (threadIdx.x == 0) lbase = (lcnt > 0) ? atomicAdd(cnt, lcnt) : 0;
  __syncthreads();
  if (v >= 0){
    int r = lbase + loc;
    act[r] = p; vox[r] = v; grid1[p] = r;
  }
}

// ---- gather winning voxel features into compact rows (Cin=4 -> float4) ----
__global__ void gather0_k(const float4* __restrict__ vf, const int* __restrict__ vox,
                          const int* __restrict__ cnt, float4* __restrict__ f0){
  int r = blockIdx.x*blockDim.x + threadIdx.x;
  if (r >= *cnt) return;
  f0[r] = vf[vox[r]];
}

// 16 FMAs on float4 registers: acc[j] += f[i] * w_i[j]
#define FMA4(acc, f, w0, w1, w2, w3)                      \
  acc.x = fmaf(f.x, w0.x, acc.x); acc.y = fmaf(f.x, w0.y, acc.y); \
  acc.z = fmaf(f.x, w0.z, acc.z); acc.w = fmaf(f.x, w0.w, acc.w); \
  acc.x = fmaf(f.y, w1.x, acc.x); acc.y = fmaf(f.y, w1.y, acc.y); \
  acc.z = fmaf(f.y, w1.z, acc.z); acc.w = fmaf(f.y, w1.w, acc.w); \
  acc.x = fmaf(f.z, w2.x, acc.x); acc.y = fmaf(f.z, w2.y, acc.y); \
  acc.z = fmaf(f.z, w2.z, acc.z); acc.w = fmaf(f.z, w2.w, acc.w); \
  acc.x = fmaf(f.w, w3.x, acc.x); acc.y = fmaf(f.w, w3.y, acc.y); \
  acc.z = fmaf(f.w, w3.z, acc.z); acc.w = fmaf(f.w, w3.w, acc.w)

template<int COUT>
__device__ __forceinline__ void bn_relu_store(float* __restrict__ fout, int r, int co,
                                              const float* __restrict__ bnp, float4 acc){
  float4 g = *(const float4*)(bnp + co);
  float4 b = *(const float4*)(bnp + COUT + co);
  float4 m = *(const float4*)(bnp + 2*COUT + co);
  float4 v = *(const float4*)(bnp + 3*COUT + co);
  float4 o;
  o.x = fmaxf((acc.x - m.x) * (g.x * rsqrtf(v.x + EPSV)) + b.x, 0.f);
  o.y = fmaxf((acc.y - m.y) * (g.y * rsqrtf(v.y + EPSV)) + b.y, 0.f);
  o.z = fmaxf((acc.z - m.z) * (g.z * rsqrtf(v.z + EPSV)) + b.z, 0.f);
  o.w = fmaxf((acc.w - m.w) * (g.w * rsqrtf(v.w + EPSV)) + b.w, 0.f);
  *(float4*)(fout + (size_t)r*COUT + co) = o;
}

// ==== unified sparse/subm conv: lockstep taps, LDS double-buffered weights,
//      grid-lookup prefetch, 2 sites x 4 couts per thread ====
template<int CIN,int COUT,bool SUBM,int DI,int HI,int WI,int DOo,int HOo,int WOo,
         int KD,int KH,int KW,int SD,int SH,int SW>
__global__ __launch_bounds__(256) void conv_lds_k(
    const float* __restrict__ fin, const float* __restrict__ w,
    const float* __restrict__ bnp, const int* __restrict__ grid,
    const int* __restrict__ act, const int* __restrict__ cnt,
    float* __restrict__ fout)
{
  constexpr int NT   = KD*KH*KW;
  constexpr int CO4  = COUT/4;
  constexpr int TAPF = CIN*COUT;          // floats per tap
  constexpr int TAP4 = TAPF/4;            // float4 per tap
  constexpr int SR   = (TAP4 + 255)/256;  // stage float4s per thread
  __shared__ __align__(16) float wbuf[2][TAPF];

  const int tid  = threadIdx.x;
  const int co   = (tid % CO4)*4;
  const int pair = tid / CO4;
  constexpr int PPB = 256/CO4;
  const int gp = blockIdx.x*PPB + pair;
  const int n  = *cnt;
  const int rA = 2*gp, rB = 2*gp + 1;
  const bool okA = rA < n, okB = rB < n;

  int zA=0,yA=0,xA=0, zB=0,yB=0,xB=0;
  if (okA){ int p = act[rA]; xA = p % WOo; int t1 = p/WOo; yA = t1 % HOo; zA = t1/HOo; }
  if (okB){ int p = act[rB]; xB = p % WOo; int t2 = p/WOo; yB = t2 % HOo; zB = t2/HOo; }

  auto gidx = [&](int kk, int z, int y, int x, bool ok)->int {
    if (!ok) return -1;
    int kd = kk/(KH*KW), kh = (kk/KW)%KH, kw2 = kk%KW;
    int zz, yy, xx;
    if (SUBM){
      zz = z + kd - 1; yy = y + kh - 1; xx = x + kw2 - 1;
      if ((unsigned)zz >= (unsigned)DI || (unsigned)yy >= (unsigned)HI ||
          (unsigned)xx >= (unsigned)WI) return -1;
    } else {
      zz = z*SD + kd; yy = y*SH + kh; xx = x*SW + kw2;
    }
    return grid[(zz*HI + yy)*WI + xx];
  };

  const float4* w4 = (const float4*)w;

  // stage tap 0 into buffer 0
  {
    float4* wb4 = (float4*)wbuf[0];
    #pragma unroll
    for (int i = 0; i < SR; i++){
      int idx = i*256 + tid;
      if (idx < TAP4) wb4[idx] = w4[idx];
    }
  }
  // prefetch tap-0 grid lookups
  int rrA = gidx(0, zA, yA, xA, okA);
  int rrB = gidx(0, zB, yB, xB, okB);
  __syncthreads();

  float4 accA = {0.f,0.f,0.f,0.f}, accB = {0.f,0.f,0.f,0.f};

  for (int kk = 0; kk < NT; kk++){
    // prefetch next tap: grid lookups + weight stage loads (latency hidden under compute)
    int rrA_n = -1, rrB_n = -1;
    float4 sreg[SR];
    if (kk + 1 < NT){
      rrA_n = gidx(kk+1, zA, yA, xA, okA);
      rrB_n = gidx(kk+1, zB, yB, xB, okB);
      #pragma unroll
      for (int i = 0; i < SR; i++){
        int idx = i*256 + tid;
        if (idx < TAP4) sreg[i] = w4[(size_t)(kk+1)*TAP4 + idx];
      }
    }

    // compute tap kk from LDS weights
    if (rrA >= 0 || rrB >= 0){
      const float* wl = wbuf[kk & 1];
      const float4* fiA = (const float4*)(fin + (size_t)(rrA < 0 ? 0 : rrA)*CIN);
      const float4* fiB = (const float4*)(fin + (size_t)(rrB < 0 ? 0 : rrB)*CIN);
      const float4 fz = {0.f,0.f,0.f,0.f};
      #pragma unroll
      for (int c4 = 0; c4 < CIN/4; c4++){
        float4 fA = (rrA >= 0) ? fiA[c4] : fz;
        float4 fB = (rrB >= 0) ? fiB[c4] : fz;
        const float* wq = wl + (size_t)c4*4*COUT + co;
        float4 w0 = *(const float4*)(wq);
        float4 w1 = *(const float4*)(wq + COUT);
        float4 w2 = *(const float4*)(wq + 2*COUT);
        float4 w3 = *(const float4*)(wq + 3*COUT);
        FMA4(accA, fA, w0, w1, w2, w3);
        FMA4(accB, fB, w0, w1, w2, w3);
      }
    }

    // commit staged weights for tap kk+1 into the other buffer
    if (kk + 1 < NT){
      float4* wb4 = (float4*)wbuf[(kk+1) & 1];
      #pragma unroll
      for (int i = 0; i < SR; i++){
        int idx = i*256 + tid;
        if (idx < TAP4) wb4[idx] = sreg[i];
      }
    }
    __syncthreads();
    rrA = rrA_n; rrB = rrB_n;
  }

  if (okA) bn_relu_store<COUT>(fout, rA, co, bnp, accA);
  if (okB) bn_relu_store<COUT>(fout, rB, co, bnp, accB);
}

// ---- build downsampled active list (block-aggregated atomics) ----
template<int DI,int HI,int WI,int DDo,int HHo,int WWo,int KD,int KH,int KW,int SD,int SH,int SW>
__global__ void build_k(const int* __restrict__ gin, int* __restrict__ gout,
                        int* __restrict__ act, int* __restrict__ cnt){
  __shared__ int lcnt, lbase;
  if (threadIdx.x == 0) lcnt = 0;
  __syncthreads();
  int p = blockIdx.x*blockDim.x + threadIdx.x;
  bool any = false;
  if (p < DDo*HHo*WWo){
    int x = p % WWo; int rem = p / WWo; int y = rem % HHo; int z = rem / HHo;
    for (int kd = 0; kd < KD; kd++)
      for (int kh = 0; kh < KH; kh++)
        for (int kw = 0; kw < KW; kw++){
          if (gin[((z*SD+kd)*HI + (y*SH+kh))*WI + (x*SW+kw)] >= 0) any = true;
        }
  }
  int loc = -1;
  if (any) loc = atomicAdd(&lcnt, 1);
  __syncthreads();
  if (threadIdx.x == 0) lbase = (lcnt > 0) ? atomicAdd(cnt, lcnt) : 0;
  __syncthreads();
  if (p < DDo*HHo*WWo){
    int r = any ? (lbase + loc) : -1;
    if (any) act[r] = p;
    gout[p] = r;
  }
}

// ---- final conv (3,1,1) stride 1 VALID, dense output; 4 couts/thread ----
template<int CIN,int COUT>
__device__ __forceinline__ void accum_tap(const float* __restrict__ fin, int rr,
                                          const float* __restrict__ wtap, int co,
                                          float4& acc){
  const float4* fi = (const float4*)(fin + (size_t)rr*CIN);
  const float* wp = wtap + co;
  #pragma unroll 4
  for (int c4 = 0; c4 < CIN/4; c4++){
    float4 f  = fi[c4];
    const float* wq = wp + (size_t)c4*4*COUT;
    float4 w0 = *(const float4*)(wq);
    float4 w1 = *(const float4*)(wq + COUT);
    float4 w2 = *(const float4*)(wq + 2*COUT);
    float4 w3 = *(const float4*)(wq + 3*COUT);
    FMA4(acc, f, w0, w1, w2, w3);
  }
}

__global__ __launch_bounds__(256) void out_conv_k(
    const float* __restrict__ f4, const float* __restrict__ w,
    const float* __restrict__ bnp, const int* __restrict__ g4,
    float* __restrict__ out){
  int t = blockIdx.x*blockDim.x + threadIdx.x;
  if (t >= SO_*32) return;
  int co = (t % 32)*4; int p = t / 32;
  int x = p % WO_; int rem = p / WO_; int y = rem % HO_; int z = rem / HO_;
  bool any = false; float4 acc = {0.f,0.f,0.f,0.f};
  for (int kd = 0; kd < 3; kd++){
    int rr = g4[((z+kd)*H4 + y)*W4 + x];
    if (rr < 0) continue;
    any = true;
    accum_tap<64,128>(f4, rr, w + (size_t)kd*64*128, co, acc);
  }
  float4 o = {0.f,0.f,0.f,0.f};
  if (any){
    float4 g = *(const float4*)(bnp + co);
    float4 b = *(const float4*)(bnp + 128 + co);
    float4 m = *(const float4*)(bnp + 2*128 + co);
    float4 v = *(const float4*)(bnp + 3*128 + co);
    o.x = fmaxf((acc.x - m.x) * (g.x * rsqrtf(v.x + EPSV)) + b.x, 0.f);
    o.y = fmaxf((acc.y - m.y) * (g.y * rsqrtf(v.y + EPSV)) + b.y, 0.f);
    o.z = fmaxf((acc.z - m.z) * (g.z * rsqrtf(v.z + EPSV)) + b.z, 0.f);
    o.w = fmaxf((acc.w - m.w) * (g.w * rsqrtf(v.w + EPSV)) + b.w, 0.f);
  }
  *(float4*)(out + (size_t)p*128 + co) = o;
}

extern "C" void kernel_launch(void* const* d_in, const int* in_sizes, int n_in,
                              void* d_out, int out_size, void* d_ws, size_t ws_size,
                              hipStream_t stream){
  const float* vf  = (const float*)d_in[0];
  const int*   vc  = (const int*)  d_in[1];
  const float* w1a = (const float*)d_in[2];  const float* bn1a = (const float*)d_in[3];
  const float* w1b = (const float*)d_in[4];  const float* bn1b = (const float*)d_in[5];
  const float* w2a = (const float*)d_in[6];  const float* bn2a = (const float*)d_in[7];
  const float* w2b = (const float*)d_in[8];  const float* bn2b = (const float*)d_in[9];
  const float* w3a = (const float*)d_in[10]; const float* bn3a = (const float*)d_in[11];
  const float* w3b = (const float*)d_in[12]; const float* bn3b = (const float*)d_in[13];
  const float* w4a = (const float*)d_in[14]; const float* bn4a = (const float*)d_in[15];
  const float* w4b = (const float*)d_in[16]; const float* bn4b = (const float*)d_in[17];
  const float* wo  = (const float*)d_in[18]; const float* bno  = (const float*)d_in[19];
  float* outp = (float*)d_out;
  int nvox = in_sizes[0] / 4;
  if (nvox > NVOX_MAX) nvox = NVOX_MAX;

  char* ws = (char*)d_ws;
  size_t off = 0;
  auto alloc = [&](size_t bytes)->void*{
    void* p = ws + off; off = (off + bytes + 255) & ~size_t(255); return p;
  };
  int* grid1 = (int*)alloc((size_t)S1*4);
  int* act1  = (int*)alloc((size_t)NVOX_MAX*4);
  int* vox1  = (int*)alloc((size_t)NVOX_MAX*4);
  int* grid2 = (int*)alloc((size_t)S2*4);
  int* act2  = (int*)alloc((size_t)S2*4);
  int* grid3 = (int*)alloc((size_t)S3*4);
  int* act3  = (int*)alloc((size_t)S3*4);
  int* grid4 = (int*)alloc((size_t)S4*4);
  int* act4  = (int*)alloc((size_t)S4*4);
  int* cnt   = (int*)alloc(8*4);
  float* f0  = (float*)alloc((size_t)NVOX_MAX*4*4);
  float* f1a = (float*)alloc((size_t)NVOX_MAX*16*4);
  float* f1b = (float*)alloc((size_t)NVOX_MAX*16*4);
  float* f2a = (float*)alloc((size_t)S2*32*4);
  float* f2b = (float*)alloc((size_t)S2*32*4);
  float* f3a = (float*)alloc((size_t)S3*64*4);
  float* f3b = (float*)alloc((size_t)S3*64*4);
  float* f4a = (float*)alloc((size_t)S4*64*4);
  float* f4b = (float*)alloc((size_t)S4*64*4);
  (void)ws_size;

  hipMemsetAsync(grid1, 0xFF, (size_t)S1*4, stream);  // -1 everywhere
  hipMemsetAsync(cnt, 0, 8*4, stream);

  const int BS = 256;
  scatter_k<<<(nvox+BS-1)/BS, BS, 0, stream>>>(vc, nvox, grid1);
  compact1_k<<<(S1+BS-1)/BS, BS, 0, stream>>>(grid1, act1, vox1, &cnt[0]);
  gather0_k<<<(nvox+BS-1)/BS, BS, 0, stream>>>((const float4*)vf, vox1, &cnt[0], (float4*)f0);

  // level 1: COUT=16 -> CO4=4 -> 128 sites/block
  conv_lds_k<4,16,true,D1,H1,W1,D1,H1,W1,3,3,3,1,1,1>
    <<<(NVOX_MAX+127)/128, BS, 0, stream>>>(f0,  w1a, bn1a, grid1, act1, &cnt[0], f1a);
  conv_lds_k<16,16,true,D1,H1,W1,D1,H1,W1,3,3,3,1,1,1>
    <<<(NVOX_MAX+127)/128, BS, 0, stream>>>(f1a, w1b, bn1b, grid1, act1, &cnt[0], f1b);

  build_k<D1,H1,W1,D2,H2,W2,3,3,3,2,2,2><<<(S2+BS-1)/BS, BS, 0, stream>>>(grid1, grid2, act2, &cnt[1]);
  // level 2: COUT=32 -> CO4=8 -> 64 sites/block
  conv_lds_k<16,32,false,D1,H1,W1,D2,H2,W2,3,3,3,2,2,2>
    <<<(S2+63)/64, BS, 0, stream>>>(f1b, w2a, bn2a, grid1, act2, &cnt[1], f2a);
  conv_lds_k<32,32,true,D2,H2,W2,D2,H2,W2,3,3,3,1,1,1>
    <<<(S2+63)/64, BS, 0, stream>>>(f2a, w2b, bn2b, grid2, act2, &cnt[1], f2b);

  build_k<D2,H2,W2,D3,H3,W3,3,3,3,2,2,2><<<(S3+BS-1)/BS, BS, 0, stream>>>(grid2, grid3, act3, &cnt[2]);
  // level 3: COUT=64 -> CO4=16 -> 32 sites/block
  conv_lds_k<32,64,false,D2,H2,W2,D3,H3,W3,3,3,3,2,2,2>
    <<<(S3+31)/32, BS, 0, stream>>>(f2b, w3a, bn3a, grid2, act3, &cnt[2], f3a);
  conv_lds_k<64,64,true,D3,H3,W3,D3,H3,W3,3,3,3,1,1,1>
    <<<(S3+31)/32, BS, 0, stream>>>(f3a, w3b, bn3b, grid3, act3, &cnt[2], f3b);

  build_k<D3,H3,W3,D4,H4,W4,3,3,3,2,2,2><<<(S4+BS-1)/BS, BS, 0, stream>>>(grid3, grid4, act4, &cnt[3]);
  // level 4: COUT=64 -> 32 sites/block
  conv_lds_k<64,64,false,D3,H3,W3,D4,H4,W4,3,3,3,2,2,2>
    <<<(S4+31)/32, BS, 0, stream>>>(f3b, w4a, bn4a, grid3, act4, &cnt[3], f4a);
  conv_lds_k<64,64,true,D4,H4,W4,D4,H4,W4,3,3,3,1,1,1>
    <<<(S4+31)/32, BS, 0, stream>>>(f4a, w4b, bn4b, grid4, act4, &cnt[3], f4b);

  out_conv_k<<<(SO_*32+BS-1)/BS, BS, 0, stream>>>(f4b, wo, bno, grid4, outp);
}

// Round 5
// 1517.300 us; speedup vs baseline: 1.5015x; 1.5015x over previous
//
#include <hip/hip_runtime.h>

#define EPSV 1e-4f

// Level geometry (derived from reference shapes)
constexpr int D1=41, H1=264, W1=264; constexpr int S1=D1*H1*W1;   // 2,857,536
constexpr int D2=20, H2=131, W2=131; constexpr int S2=D2*H2*W2;   //   343,220
constexpr int D3=9,  H3=65,  W3=65;  constexpr int S3=D3*H3*W3;   //    38,025
constexpr int D4=4,  H4=32,  W4=32;  constexpr int S4=D4*H4*W4;   //     4,096
constexpr int DO_=2, HO_=32, WO_=32; constexpr int SO_=DO_*HO_*WO_; //   2,048
constexpr int NVOX_MAX=80000;

// ---- scatter voxel indices into dense grid; last-write-wins == max index (matches np) ----
__global__ void scatter_k(const int* __restrict__ coords, int n, int* __restrict__ grid1){
  int i = blockIdx.x*blockDim.x + threadIdx.x;
  if (i >= n) return;
  int z = coords[i*4+1], y = coords[i*4+2], x = coords[i*4+3];
  atomicMax(&grid1[(z*H1 + y)*W1 + x], i);
}

// ---- compact active sites of level 1 (block-aggregated atomics) ----
__global__ void compact1_k(int* __restrict__ grid1, int* __restrict__ act,
                           int* __restrict__ vox, int* __restrict__ cnt){
  __shared__ int lcnt, lbase;
  if (threadIdx.x == 0) lcnt = 0;
  __syncthreads();
  int p = blockIdx.x*blockDim.x + threadIdx.x;
  int v = (p < S1) ? grid1[p] : -1;
  int loc = -1;
  if (v >= 0) loc = atomicAdd(&lcnt, 1);
  __syncthreads();
  if (threadIdx.x == 0) lbase = (lcnt > 0) ? atomicAdd(cnt, lcnt) : 0;
  __syncthreads();
  if (v >= 0){
    int r = lbase + loc;
    act[r] = p; vox[r] = v; grid1[p] = r;
  }
}

// ---- gather winning voxel features into compact rows (Cin=4 -> float4) ----
__global__ void gather0_k(const float4* __restrict__ vf, const int* __restrict__ vox,
                          const int* __restrict__ cnt, float4* __restrict__ f0){
  int r = blockIdx.x*blockDim.x + threadIdx.x;
  if (r >= *cnt) return;
  f0[r] = vf[vox[r]];
}

// 16 FMAs on float4 registers: acc[j] += f[i] * w_i[j]
#define FMA4(acc, f, w0, w1, w2, w3)                      \
  acc.x = fmaf(f.x, w0.x, acc.x); acc.y = fmaf(f.x, w0.y, acc.y); \
  acc.z = fmaf(f.x, w0.z, acc.z); acc.w = fmaf(f.x, w0.w, acc.w); \
  acc.x = fmaf(f.y, w1.x, acc.x); acc.y = fmaf(f.y, w1.y, acc.y); \
  acc.z = fmaf(f.y, w1.z, acc.z); acc.w = fmaf(f.y, w1.w, acc.w); \
  acc.x = fmaf(f.z, w2.x, acc.x); acc.y = fmaf(f.z, w2.y, acc.y); \
  acc.z = fmaf(f.z, w2.z, acc.z); acc.w = fmaf(f.z, w2.w, acc.w); \
  acc.x = fmaf(f.w, w3.x, acc.x); acc.y = fmaf(f.w, w3.y, acc.y); \
  acc.z = fmaf(f.w, w3.z, acc.z); acc.w = fmaf(f.w, w3.w, acc.w)

template<int COUT>
__device__ __forceinline__ void bn_relu_store(float* __restrict__ fout, int r, int co,
                                              const float* __restrict__ bnp, float4 acc){
  float4 g = *(const float4*)(bnp + co);
  float4 b = *(const float4*)(bnp + COUT + co);
  float4 m = *(const float4*)(bnp + 2*COUT + co);
  float4 v = *(const float4*)(bnp + 3*COUT + co);
  float4 o;
  o.x = fmaxf((acc.x - m.x) * (g.x * rsqrtf(v.x + EPSV)) + b.x, 0.f);
  o.y = fmaxf((acc.y - m.y) * (g.y * rsqrtf(v.y + EPSV)) + b.y, 0.f);
  o.z = fmaxf((acc.z - m.z) * (g.z * rsqrtf(v.z + EPSV)) + b.z, 0.f);
  o.w = fmaxf((acc.w - m.w) * (g.w * rsqrtf(v.w + EPSV)) + b.w, 0.f);
  *(float4*)(fout + (size_t)r*COUT + co) = o;
}

// ==== sparse/subm conv: lane=site, wave=uniform cout-block (scalar-path weights),
//      grid lookups prefetched 2 taps ahead, zero barriers ====
template<int CIN,int COUT,bool SUBM,int DI,int HI,int WI,int HOo,int WOo,
         int SD,int SH,int SW>
__global__ __launch_bounds__(256) void conv_sw_k(
    const float* __restrict__ fin, const float* __restrict__ w,
    const float* __restrict__ bnp, const int* __restrict__ grid,
    const int* __restrict__ act, const int* __restrict__ cnt,
    float* __restrict__ fout)
{
  constexpr int NT  = 27;
  constexpr int CBG = COUT/16;     // cout-block groups per site-block (4 waves each)
  const int lane = threadIdx.x & 63;
  const int wave = threadIdx.x >> 6;
  const int sblk = blockIdx.x / CBG;
  const int cbg  = blockIdx.x % CBG;
  int co = (cbg*4 + wave)*4;
  co = __builtin_amdgcn_readfirstlane(co);   // pin wave-uniform -> weights go scalar path
  const int n = *cnt;
  if (sblk*64 >= n) return;                  // uniform: whole site-block inactive
  const int r = sblk*64 + lane;
  const bool ok = r < n;

  int z=0, y=0, x=0;
  if (ok){ int p = act[r]; x = p % WOo; int t1 = p/WOo; y = t1 % HOo; z = t1/HOo; }

  auto gidx = [&](int kk)->int {
    if (!ok) return -1;
    int kd = kk/9, kh = (kk/3)%3, kw2 = kk%3;
    if (SUBM){
      if (kk == 13) return r;                // center tap = self
      int zz = z + kd - 1, yy = y + kh - 1, xx = x + kw2 - 1;
      if ((unsigned)zz >= (unsigned)DI || (unsigned)yy >= (unsigned)HI ||
          (unsigned)xx >= (unsigned)WI) return -1;
      return grid[(zz*HI + yy)*WI + xx];
    } else {
      int zz = z*SD + kd, yy = y*SH + kh, xx = x*SW + kw2;  // VALID: always in bounds
      return grid[(zz*HI + yy)*WI + xx];
    }
  };

  float4 acc = {0.f,0.f,0.f,0.f};
  int rr0 = gidx(0);
  int rr1 = gidx(1);
  #pragma unroll 1
  for (int kk = 0; kk < NT; kk++){
    int rrn = (kk + 2 < NT) ? gidx(kk+2) : -1;   // prefetch 2 taps ahead
    if (rr0 >= 0){
      const float4* fi = (const float4*)(fin + (size_t)rr0*CIN);
      const float* wt = w + (size_t)kk*CIN*COUT + co;   // uniform address
      #pragma unroll 4
      for (int c4 = 0; c4 < CIN/4; c4++){
        float4 f  = fi[c4];
        const float* wq = wt + c4*4*COUT;
        float4 w0 = *(const float4*)(wq);
        float4 w1 = *(const float4*)(wq + COUT);
        float4 w2 = *(const float4*)(wq + 2*COUT);
        float4 w3 = *(const float4*)(wq + 3*COUT);
        FMA4(acc, f, w0, w1, w2, w3);
      }
    }
    rr0 = rr1; rr1 = rrn;
  }
  if (ok) bn_relu_store<COUT>(fout, r, co, bnp, acc);
}

// ---- build downsampled active list (block-aggregated atomics) ----
template<int DI,int HI,int WI,int DDo,int HHo,int WWo,int KD,int KH,int KW,int SD,int SH,int SW>
__global__ void build_k(const int* __restrict__ gin, int* __restrict__ gout,
                        int* __restrict__ act, int* __restrict__ cnt){
  __shared__ int lcnt, lbase;
  if (threadIdx.x == 0) lcnt = 0;
  __syncthreads();
  int p = blockIdx.x*blockDim.x + threadIdx.x;
  bool any = false;
  if (p < DDo*HHo*WWo){
    int x = p % WWo; int rem = p / WWo; int y = rem % HHo; int z = rem / HHo;
    for (int kd = 0; kd < KD; kd++)
      for (int kh = 0; kh < KH; kh++)
        for (int kw = 0; kw < KW; kw++){
          if (gin[((z*SD+kd)*HI + (y*SH+kh))*WI + (x*SW+kw)] >= 0) any = true;
        }
  }
  int loc = -1;
  if (any) loc = atomicAdd(&lcnt, 1);
  __syncthreads();
  if (threadIdx.x == 0) lbase = (lcnt > 0) ? atomicAdd(cnt, lcnt) : 0;
  __syncthreads();
  if (p < DDo*HHo*WWo){
    int r = any ? (lbase + loc) : -1;
    if (any) act[r] = p;
    gout[p] = r;
  }
}

// ---- final conv (3,1,1) stride 1 VALID, dense output; 4 couts/thread ----
template<int CIN,int COUT>
__device__ __forceinline__ void accum_tap(const float* __restrict__ fin, int rr,
                                          const float* __restrict__ wtap, int co,
                                          float4& acc){
  const float4* fi = (const float4*)(fin + (size_t)rr*CIN);
  const float* wp = wtap + co;
  #pragma unroll 4
  for (int c4 = 0; c4 < CIN/4; c4++){
    float4 f  = fi[c4];
    const float* wq = wp + (size_t)c4*4*COUT;
    float4 w0 = *(const float4*)(wq);
    float4 w1 = *(const float4*)(wq + COUT);
    float4 w2 = *(const float4*)(wq + 2*COUT);
    float4 w3 = *(const float4*)(wq + 3*COUT);
    FMA4(acc, f, w0, w1, w2, w3);
  }
}

__global__ __launch_bounds__(256) void out_conv_k(
    const float* __restrict__ f4, const float* __restrict__ w,
    const float* __restrict__ bnp, const int* __restrict__ g4,
    float* __restrict__ out){
  int t = blockIdx.x*blockDim.x + threadIdx.x;
  if (t >= SO_*32) return;
  int co = (t % 32)*4; int p = t / 32;
  int x = p % WO_; int rem = p / WO_; int y = rem % HO_; int z = rem / HO_;
  bool any = false; float4 acc = {0.f,0.f,0.f,0.f};
  for (int kd = 0; kd < 3; kd++){
    int rr = g4[((z+kd)*H4 + y)*W4 + x];
    if (rr < 0) continue;
    any = true;
    accum_tap<64,128>(f4, rr, w + (size_t)kd*64*128, co, acc);
  }
  float4 o = {0.f,0.f,0.f,0.f};
  if (any){
    float4 g = *(const float4*)(bnp + co);
    float4 b = *(const float4*)(bnp + 128 + co);
    float4 m = *(const float4*)(bnp + 2*128 + co);
    float4 v = *(const float4*)(bnp + 3*128 + co);
    o.x = fmaxf((acc.x - m.x) * (g.x * rsqrtf(v.x + EPSV)) + b.x, 0.f);
    o.y = fmaxf((acc.y - m.y) * (g.y * rsqrtf(v.y + EPSV)) + b.y, 0.f);
    o.z = fmaxf((acc.z - m.z) * (g.z * rsqrtf(v.z + EPSV)) + b.z, 0.f);
    o.w = fmaxf((acc.w - m.w) * (g.w * rsqrtf(v.w + EPSV)) + b.w, 0.f);
  }
  *(float4*)(out + (size_t)p*128 + co) = o;
}

extern "C" void kernel_launch(void* const* d_in, const int* in_sizes, int n_in,
                              void* d_out, int out_size, void* d_ws, size_t ws_size,
                              hipStream_t stream){
  const float* vf  = (const float*)d_in[0];
  const int*   vc  = (const int*)  d_in[1];
  const float* w1a = (const float*)d_in[2];  const float* bn1a = (const float*)d_in[3];
  const float* w1b = (const float*)d_in[4];  const float* bn1b = (const float*)d_in[5];
  const float* w2a = (const float*)d_in[6];  const float* bn2a = (const float*)d_in[7];
  const float* w2b = (const float*)d_in[8];  const float* bn2b = (const float*)d_in[9];
  const float* w3a = (const float*)d_in[10]; const float* bn3a = (const float*)d_in[11];
  const float* w3b = (const float*)d_in[12]; const float* bn3b = (const float*)d_in[13];
  const float* w4a = (const float*)d_in[14]; const float* bn4a = (const float*)d_in[15];
  const float* w4b = (const float*)d_in[16]; const float* bn4b = (const float*)d_in[17];
  const float* wo  = (const float*)d_in[18]; const float* bno  = (const float*)d_in[19];
  float* outp = (float*)d_out;
  int nvox = in_sizes[0] / 4;
  if (nvox > NVOX_MAX) nvox = NVOX_MAX;

  char* ws = (char*)d_ws;
  size_t off = 0;
  auto alloc = [&](size_t bytes)->void*{
    void* p = ws + off; off = (off + bytes + 255) & ~size_t(255); return p;
  };
  int* grid1 = (int*)alloc((size_t)S1*4);
  int* act1  = (int*)alloc((size_t)NVOX_MAX*4);
  int* vox1  = (int*)alloc((size_t)NVOX_MAX*4);
  int* grid2 = (int*)alloc((size_t)S2*4);
  int* act2  = (int*)alloc((size_t)S2*4);
  int* grid3 = (int*)alloc((size_t)S3*4);
  int* act3  = (int*)alloc((size_t)S3*4);
  int* grid4 = (int*)alloc((size_t)S4*4);
  int* act4  = (int*)alloc((size_t)S4*4);
  int* cnt   = (int*)alloc(8*4);
  float* f0  = (float*)alloc((size_t)NVOX_MAX*4*4);
  float* f1a = (float*)alloc((size_t)NVOX_MAX*16*4);
  float* f1b = (float*)alloc((size_t)NVOX_MAX*16*4);
  float* f2a = (float*)alloc((size_t)S2*32*4);
  float* f2b = (float*)alloc((size_t)S2*32*4);
  float* f3a = (float*)alloc((size_t)S3*64*4);
  float* f3b = (float*)alloc((size_t)S3*64*4);
  float* f4a = (float*)alloc((size_t)S4*64*4);
  float* f4b = (float*)alloc((size_t)S4*64*4);
  (void)ws_size;

  hipMemsetAsync(grid1, 0xFF, (size_t)S1*4, stream);  // -1 everywhere
  hipMemsetAsync(cnt, 0, 8*4, stream);

  const int BS = 256;
  scatter_k<<<(nvox+BS-1)/BS, BS, 0, stream>>>(vc, nvox, grid1);
  compact1_k<<<(S1+BS-1)/BS, BS, 0, stream>>>(grid1, act1, vox1, &cnt[0]);
  gather0_k<<<(nvox+BS-1)/BS, BS, 0, stream>>>((const float4*)vf, vox1, &cnt[0], (float4*)f0);

  auto sb = [](int maxN){ return (maxN + 63)/64; };

  // level 1 (COUT=16 -> CBG=1)
  conv_sw_k<4,16,true,D1,H1,W1,H1,W1,1,1,1>
    <<<sb(NVOX_MAX)*1, BS, 0, stream>>>(f0,  w1a, bn1a, grid1, act1, &cnt[0], f1a);
  conv_sw_k<16,16,true,D1,H1,W1,H1,W1,1,1,1>
    <<<sb(NVOX_MAX)*1, BS, 0, stream>>>(f1a, w1b, bn1b, grid1, act1, &cnt[0], f1b);

  build_k<D1,H1,W1,D2,H2,W2,3,3,3,2,2,2><<<(S2+BS-1)/BS, BS, 0, stream>>>(grid1, grid2, act2, &cnt[1]);
  // level 2 (COUT=32 -> CBG=2)
  conv_sw_k<16,32,false,D1,H1,W1,H2,W2,2,2,2>
    <<<sb(S2)*2, BS, 0, stream>>>(f1b, w2a, bn2a, grid1, act2, &cnt[1], f2a);
  conv_sw_k<32,32,true,D2,H2,W2,H2,W2,1,1,1>
    <<<sb(S2)*2, BS, 0, stream>>>(f2a, w2b, bn2b, grid2, act2, &cnt[1], f2b);

  build_k<D2,H2,W2,D3,H3,W3,3,3,3,2,2,2><<<(S3+BS-1)/BS, BS, 0, stream>>>(grid2, grid3, act3, &cnt[2]);
  // level 3 (COUT=64 -> CBG=4)
  conv_sw_k<32,64,false,D2,H2,W2,H3,W3,2,2,2>
    <<<sb(S3)*4, BS, 0, stream>>>(f2b, w3a, bn3a, grid2, act3, &cnt[2], f3a);
  conv_sw_k<64,64,true,D3,H3,W3,H3,W3,1,1,1>
    <<<sb(S3)*4, BS, 0, stream>>>(f3a, w3b, bn3b, grid3, act3, &cnt[2], f3b);

  build_k<D3,H3,W3,D4,H4,W4,3,3,3,2,2,2><<<(S4+BS-1)/BS, BS, 0, stream>>>(grid3, grid4, act4, &cnt[3]);
  // level 4 (COUT=64 -> CBG=4)
  conv_sw_k<64,64,false,D3,H3,W3,H4,W4,2,2,2>
    <<<sb(S4)*4, BS, 0, stream>>>(f3b, w4a, bn4a, grid3, act4, &cnt[3], f4a);
  conv_sw_k<64,64,true,D4,H4,W4,H4,W4,1,1,1>
    <<<sb(S4)*4, BS, 0, stream>>>(f4a, w4b, bn4b, grid4, act4, &cnt[3], f4b);

  out_conv_k<<<(SO_*32+BS-1)/BS, BS, 0, stream>>>(f4b, wo, bno, grid4, outp);
}

// Round 6
// 1076.423 us; speedup vs baseline: 2.1165x; 1.4096x over previous
//
#include <hip/hip_runtime.h>

#define EPSV 1e-4f

// Level geometry (derived from reference shapes)
constexpr int D1=41, H1=264, W1=264; constexpr int S1=D1*H1*W1;   // 2,857,536
constexpr int D2=20, H2=131, W2=131; constexpr int S2=D2*H2*W2;   //   343,220
constexpr int D3=9,  H3=65,  W3=65;  constexpr int S3=D3*H3*W3;   //    38,025
constexpr int D4=4,  H4=32,  W4=32;  constexpr int S4=D4*H4*W4;   //     4,096
constexpr int DO_=2, HO_=32, WO_=32; constexpr int SO_=DO_*HO_*WO_; //   2,048
constexpr int NVOX_MAX=80000;

// ---- scatter voxel indices into dense grid; last-write-wins == max index (matches np) ----
__global__ void scatter_k(const int* __restrict__ coords, int n, int* __restrict__ grid1){
  int i = blockIdx.x*blockDim.x + threadIdx.x;
  if (i >= n) return;
  int z = coords[i*4+1], y = coords[i*4+2], x = coords[i*4+3];
  atomicMax(&grid1[(z*H1 + y)*W1 + x], i);
}

// ---- compact active sites of level 1 (block-aggregated atomics) ----
__global__ void compact1_k(int* __restrict__ grid1, int* __restrict__ act,
                           int* __restrict__ vox, int* __restrict__ cnt){
  __shared__ int lcnt, lbase;
  if (threadIdx.x == 0) lcnt = 0;
  __syncthreads();
  int p = blockIdx.x*blockDim.x + threadIdx.x;
  int v = (p < S1) ? grid1[p] : -1;
  int loc = -1;
  if (v >= 0) loc = atomicAdd(&lcnt, 1);
  __syncthreads();
  if (threadIdx.x == 0) lbase = (lcnt > 0) ? atomicAdd(cnt, lcnt) : 0;
  __syncthreads();
  if (v >= 0){
    int r = lbase + loc;
    act[r] = p; vox[r] = v; grid1[p] = r;
  }
}

// ---- gather winning voxel features into compact rows (Cin=4 -> float4) ----
__global__ void gather0_k(const float4* __restrict__ vf, const int* __restrict__ vox,
                          const int* __restrict__ cnt, float4* __restrict__ f0){
  int r = blockIdx.x*blockDim.x + threadIdx.x;
  if (r >= *cnt) return;
  f0[r] = vf[vox[r]];
}

// 16 FMAs on float4 registers: acc[j] += f[i] * w_i[j]
#define FMA4(acc, f, w0, w1, w2, w3)                      \
  acc.x = fmaf(f.x, w0.x, acc.x); acc.y = fmaf(f.x, w0.y, acc.y); \
  acc.z = fmaf(f.x, w0.z, acc.z); acc.w = fmaf(f.x, w0.w, acc.w); \
  acc.x = fmaf(f.y, w1.x, acc.x); acc.y = fmaf(f.y, w1.y, acc.y); \
  acc.z = fmaf(f.y, w1.z, acc.z); acc.w = fmaf(f.y, w1.w, acc.w); \
  acc.x = fmaf(f.z, w2.x, acc.x); acc.y = fmaf(f.z, w2.y, acc.y); \
  acc.z = fmaf(f.z, w2.z, acc.z); acc.w = fmaf(f.z, w2.w, acc.w); \
  acc.x = fmaf(f.w, w3.x, acc.x); acc.y = fmaf(f.w, w3.y, acc.y); \
  acc.z = fmaf(f.w, w3.z, acc.z); acc.w = fmaf(f.w, w3.w, acc.w)

template<int COUT>
__device__ __forceinline__ void bn_relu_store(float* __restrict__ fout, int r, int co,
                                              const float* __restrict__ bnp, float4 acc){
  float4 g = *(const float4*)(bnp + co);
  float4 b = *(const float4*)(bnp + COUT + co);
  float4 m = *(const float4*)(bnp + 2*COUT + co);
  float4 v = *(const float4*)(bnp + 3*COUT + co);
  float4 o;
  o.x = fmaxf((acc.x - m.x) * (g.x * rsqrtf(v.x + EPSV)) + b.x, 0.f);
  o.y = fmaxf((acc.y - m.y) * (g.y * rsqrtf(v.y + EPSV)) + b.y, 0.f);
  o.z = fmaxf((acc.z - m.z) * (g.z * rsqrtf(v.z + EPSV)) + b.z, 0.f);
  o.w = fmaxf((acc.w - m.w) * (g.w * rsqrtf(v.w + EPSV)) + b.w, 0.f);
  *(float4*)(fout + (size_t)r*COUT + co) = o;
}

// ==== sparse/subm conv: lane=site, wave=(site-block, cout-group of 8),
//      weights on scalar path, grid prefetch 2 taps ahead, zero barriers ====
template<int CIN,int COUT,bool SUBM,int DI,int HI,int WI,int HOo,int WOo,
         int SD,int SH,int SW>
__global__ __launch_bounds__(256) void conv_sw_k(
    const float* __restrict__ fin, const float* __restrict__ w,
    const float* __restrict__ bnp, const int* __restrict__ grid,
    const int* __restrict__ act, const int* __restrict__ cnt,
    float* __restrict__ fout)
{
  constexpr int NT  = 27;
  constexpr int NCO = 8;              // couts per lane
  constexpr int NCG = COUT/NCO;       // cout groups per site-block
  const int lane = threadIdx.x & 63;
  const int wgl  = blockIdx.x*4 + (threadIdx.x >> 6);   // global wave id
  const int sblk = wgl / NCG;
  const int cg   = wgl % NCG;
  int co = __builtin_amdgcn_readfirstlane(cg*NCO);      // weights -> scalar path
  const int n = *cnt;
  if (sblk*64 >= n) return;           // wave-uniform exit
  const int r = sblk*64 + lane;
  const bool ok = r < n;

  int z=0, y=0, x=0;
  if (ok){ int p = act[r]; x = p % WOo; int t1 = p/WOo; y = t1 % HOo; z = t1/HOo; }

  auto gidx = [&](int kk)->int {
    if (!ok) return -1;
    int kd = kk/9, kh = (kk/3)%3, kw2 = kk%3;
    if (SUBM){
      if (kk == 13) return r;                // center tap = self
      int zz = z + kd - 1, yy = y + kh - 1, xx = x + kw2 - 1;
      if ((unsigned)zz >= (unsigned)DI || (unsigned)yy >= (unsigned)HI ||
          (unsigned)xx >= (unsigned)WI) return -1;
      return grid[(zz*HI + yy)*WI + xx];
    } else {
      int zz = z*SD + kd, yy = y*SH + kh, xx = x*SW + kw2;  // VALID: in bounds
      return grid[(zz*HI + yy)*WI + xx];
    }
  };

  float4 acc0 = {0.f,0.f,0.f,0.f}, acc1 = {0.f,0.f,0.f,0.f};
  int rr0 = gidx(0);
  int rr1 = gidx(1);
  #pragma unroll 1
  for (int kk = 0; kk < NT; kk++){
    int rrn = (kk + 2 < NT) ? gidx(kk+2) : -1;   // prefetch 2 taps ahead
    if (rr0 >= 0){
      const float4* fi = (const float4*)(fin + (size_t)rr0*CIN);
      const float* wt = w + (size_t)kk*CIN*COUT + co;   // uniform address
      #pragma unroll 8
      for (int c4 = 0; c4 < CIN/4; c4++){
        float4 f  = fi[c4];
        const float* wq = wt + c4*4*COUT;
        // acc0: couts co..co+3
        {
          float4 w0 = *(const float4*)(wq);
          float4 w1 = *(const float4*)(wq + COUT);
          float4 w2 = *(const float4*)(wq + 2*COUT);
          float4 w3 = *(const float4*)(wq + 3*COUT);
          FMA4(acc0, f, w0, w1, w2, w3);
        }
        // acc1: couts co+4..co+7
        {
          float4 w0 = *(const float4*)(wq + 4);
          float4 w1 = *(const float4*)(wq + COUT + 4);
          float4 w2 = *(const float4*)(wq + 2*COUT + 4);
          float4 w3 = *(const float4*)(wq + 3*COUT + 4);
          FMA4(acc1, f, w0, w1, w2, w3);
        }
      }
    }
    rr0 = rr1; rr1 = rrn;
  }
  if (ok){
    bn_relu_store<COUT>(fout, r, co,     bnp, acc0);
    bn_relu_store<COUT>(fout, r, co + 4, bnp, acc1);
  }
}

// ---- build downsampled active list (block-aggregated atomics) ----
template<int DI,int HI,int WI,int DDo,int HHo,int WWo,int KD,int KH,int KW,int SD,int SH,int SW>
__global__ void build_k(const int* __restrict__ gin, int* __restrict__ gout,
                        int* __restrict__ act, int* __restrict__ cnt){
  __shared__ int lcnt, lbase;
  if (threadIdx.x == 0) lcnt = 0;
  __syncthreads();
  int p = blockIdx.x*blockDim.x + threadIdx.x;
  bool any = false;
  if (p < DDo*HHo*WWo){
    int x = p % WWo; int rem = p / WWo; int y = rem % HHo; int z = rem / HHo;
    for (int kd = 0; kd < KD; kd++)
      for (int kh = 0; kh < KH; kh++)
        for (int kw = 0; kw < KW; kw++){
          if (gin[((z*SD+kd)*HI + (y*SH+kh))*WI + (x*SW+kw)] >= 0) any = true;
        }
  }
  int loc = -1;
  if (any) loc = atomicAdd(&lcnt, 1);
  __syncthreads();
  if (threadIdx.x == 0) lbase = (lcnt > 0) ? atomicAdd(cnt, lcnt) : 0;
  __syncthreads();
  if (p < DDo*HHo*WWo){
    int r = any ? (lbase + loc) : -1;
    if (any) act[r] = p;
    gout[p] = r;
  }
}

// ---- final conv (3,1,1) stride 1 VALID, dense output; 4 couts/thread ----
template<int CIN,int COUT>
__device__ __forceinline__ void accum_tap(const float* __restrict__ fin, int rr,
                                          const float* __restrict__ wtap, int co,
                                          float4& acc){
  const float4* fi = (const float4*)(fin + (size_t)rr*CIN);
  const float* wp = wtap + co;
  #pragma unroll 4
  for (int c4 = 0; c4 < CIN/4; c4++){
    float4 f  = fi[c4];
    const float* wq = wp + (size_t)c4*4*COUT;
    float4 w0 = *(const float4*)(wq);
    float4 w1 = *(const float4*)(wq + COUT);
    float4 w2 = *(const float4*)(wq + 2*COUT);
    float4 w3 = *(const float4*)(wq + 3*COUT);
    FMA4(acc, f, w0, w1, w2, w3);
  }
}

__global__ __launch_bounds__(256) void out_conv_k(
    const float* __restrict__ f4, const float* __restrict__ w,
    const float* __restrict__ bnp, const int* __restrict__ g4,
    float* __restrict__ out){
  int t = blockIdx.x*blockDim.x + threadIdx.x;
  if (t >= SO_*32) return;
  int co = (t % 32)*4; int p = t / 32;
  int x = p % WO_; int rem = p / WO_; int y = rem % HO_; int z = rem / HO_;
  bool any = false; float4 acc = {0.f,0.f,0.f,0.f};
  for (int kd = 0; kd < 3; kd++){
    int rr = g4[((z+kd)*H4 + y)*W4 + x];
    if (rr < 0) continue;
    any = true;
    accum_tap<64,128>(f4, rr, w + (size_t)kd*64*128, co, acc);
  }
  float4 o = {0.f,0.f,0.f,0.f};
  if (any){
    float4 g = *(const float4*)(bnp + co);
    float4 b = *(const float4*)(bnp + 128 + co);
    float4 m = *(const float4*)(bnp + 2*128 + co);
    float4 v = *(const float4*)(bnp + 3*128 + co);
    o.x = fmaxf((acc.x - m.x) * (g.x * rsqrtf(v.x + EPSV)) + b.x, 0.f);
    o.y = fmaxf((acc.y - m.y) * (g.y * rsqrtf(v.y + EPSV)) + b.y, 0.f);
    o.z = fmaxf((acc.z - m.z) * (g.z * rsqrtf(v.z + EPSV)) + b.z, 0.f);
    o.w = fmaxf((acc.w - m.w) * (g.w * rsqrtf(v.w + EPSV)) + b.w, 0.f);
  }
  *(float4*)(out + (size_t)p*128 + co) = o;
}

extern "C" void kernel_launch(void* const* d_in, const int* in_sizes, int n_in,
                              void* d_out, int out_size, void* d_ws, size_t ws_size,
                              hipStream_t stream){
  const float* vf  = (const float*)d_in[0];
  const int*   vc  = (const int*)  d_in[1];
  const float* w1a = (const float*)d_in[2];  const float* bn1a = (const float*)d_in[3];
  const float* w1b = (const float*)d_in[4];  const float* bn1b = (const float*)d_in[5];
  const float* w2a = (const float*)d_in[6];  const float* bn2a = (const float*)d_in[7];
  const float* w2b = (const float*)d_in[8];  const float* bn2b = (const float*)d_in[9];
  const float* w3a = (const float*)d_in[10]; const float* bn3a = (const float*)d_in[11];
  const float* w3b = (const float*)d_in[12]; const float* bn3b = (const float*)d_in[13];
  const float* w4a = (const float*)d_in[14]; const float* bn4a = (const float*)d_in[15];
  const float* w4b = (const float*)d_in[16]; const float* bn4b = (const float*)d_in[17];
  const float* wo  = (const float*)d_in[18]; const float* bno  = (const float*)d_in[19];
  float* outp = (float*)d_out;
  int nvox = in_sizes[0] / 4;
  if (nvox > NVOX_MAX) nvox = NVOX_MAX;

  char* ws = (char*)d_ws;
  size_t off = 0;
  auto alloc = [&](size_t bytes)->void*{
    void* p = ws + off; off = (off + bytes + 255) & ~size_t(255); return p;
  };
  int* grid1 = (int*)alloc((size_t)S1*4);
  int* act1  = (int*)alloc((size_t)NVOX_MAX*4);
  int* vox1  = (int*)alloc((size_t)NVOX_MAX*4);
  int* grid2 = (int*)alloc((size_t)S2*4);
  int* act2  = (int*)alloc((size_t)S2*4);
  int* grid3 = (int*)alloc((size_t)S3*4);
  int* act3  = (int*)alloc((size_t)S3*4);
  int* grid4 = (int*)alloc((size_t)S4*4);
  int* act4  = (int*)alloc((size_t)S4*4);
  int* cnt   = (int*)alloc(8*4);
  float* f0  = (float*)alloc((size_t)NVOX_MAX*4*4);
  float* f1a = (float*)alloc((size_t)NVOX_MAX*16*4);
  float* f1b = (float*)alloc((size_t)NVOX_MAX*16*4);
  float* f2a = (float*)alloc((size_t)S2*32*4);
  float* f2b = (float*)alloc((size_t)S2*32*4);
  float* f3a = (float*)alloc((size_t)S3*64*4);
  float* f3b = (float*)alloc((size_t)S3*64*4);
  float* f4a = (float*)alloc((size_t)S4*64*4);
  float* f4b = (float*)alloc((size_t)S4*64*4);
  (void)ws_size;

  hipMemsetAsync(grid1, 0xFF, (size_t)S1*4, stream);  // -1 everywhere
  hipMemsetAsync(cnt, 0, 8*4, stream);

  const int BS = 256;
  scatter_k<<<(nvox+BS-1)/BS, BS, 0, stream>>>(vc, nvox, grid1);
  compact1_k<<<(S1+BS-1)/BS, BS, 0, stream>>>(grid1, act1, vox1, &cnt[0]);
  gather0_k<<<(nvox+BS-1)/BS, BS, 0, stream>>>((const float4*)vf, vox1, &cnt[0], (float4*)f0);

  // blocks = ceil(siteBlocks * NCG / 4), NCG = COUT/8
  auto nblk = [](int maxN, int cout){ int waves = ((maxN+63)/64) * (cout/8); return (waves+3)/4; };

  // level 1 (COUT=16)
  conv_sw_k<4,16,true,D1,H1,W1,H1,W1,1,1,1>
    <<<nblk(NVOX_MAX,16), BS, 0, stream>>>(f0,  w1a, bn1a, grid1, act1, &cnt[0], f1a);
  conv_sw_k<16,16,true,D1,H1,W1,H1,W1,1,1,1>
    <<<nblk(NVOX_MAX,16), BS, 0, stream>>>(f1a, w1b, bn1b, grid1, act1, &cnt[0], f1b);

  build_k<D1,H1,W1,D2,H2,W2,3,3,3,2,2,2><<<(S2+BS-1)/BS, BS, 0, stream>>>(grid1, grid2, act2, &cnt[1]);
  // level 2 (COUT=32)
  conv_sw_k<16,32,false,D1,H1,W1,H2,W2,2,2,2>
    <<<nblk(S2,32), BS, 0, stream>>>(f1b, w2a, bn2a, grid1, act2, &cnt[1], f2a);
  conv_sw_k<32,32,true,D2,H2,W2,H2,W2,1,1,1>
    <<<nblk(S2,32), BS, 0, stream>>>(f2a, w2b, bn2b, grid2, act2, &cnt[1], f2b);

  build_k<D2,H2,W2,D3,H3,W3,3,3,3,2,2,2><<<(S3+BS-1)/BS, BS, 0, stream>>>(grid2, grid3, act3, &cnt[2]);
  // level 3 (COUT=64)
  conv_sw_k<32,64,false,D2,H2,W2,H3,W3,2,2,2>
    <<<nblk(S3,64), BS, 0, stream>>>(f2b, w3a, bn3a, grid2, act3, &cnt[2], f3a);
  conv_sw_k<64,64,true,D3,H3,W3,H3,W3,1,1,1>
    <<<nblk(S3,64), BS, 0, stream>>>(f3a, w3b, bn3b, grid3, act3, &cnt[2], f3b);

  build_k<D3,H3,W3,D4,H4,W4,3,3,3,2,2,2><<<(S4+BS-1)/BS, BS, 0, stream>>>(grid3, grid4, act4, &cnt[3]);
  // level 4 (COUT=64)
  conv_sw_k<64,64,false,D3,H3,W3,H4,W4,2,2,2>
    <<<nblk(S4,64), BS, 0, stream>>>(f3b, w4a, bn4a, grid3, act4, &cnt[3], f4a);
  conv_sw_k<64,64,true,D4,H4,W4,H4,W4,1,1,1>
    <<<nblk(S4,64), BS, 0, stream>>>(f4a, w4b, bn4b, grid4, act4, &cnt[3], f4b);

  out_conv_k<<<(SO_*32+BS-1)/BS, BS, 0, stream>>>(f4b, wo, bno, grid4, outp);
}